// Round 8
// baseline (127.022 us; speedup 1.0000x reference)
//
#include <hip/hip_runtime.h>
#include <hip/hip_bf16.h>

// feature [B=128, E=64, D=128] fp32 -> N = 8192 rows of dim 128.
// loss = mean_r( log(den_r) - log(pos_r) ),
//   den_r = sum_c exp(10*<f_r,f_c>), pos_r = sum over c in r's 64-row block.
//
// v8: v1's verified dbuf-LDS pipeline, re-dimensioned for occupancy.
// All variants share the 8.3us MFMA floor; v1 ran it at 28% because 64KB LDS
// capped residency at 2 blocks/CU (every wave drains the same barrier).
// Now: stage-step = 64 B-rows (16KB), dbuf -> 32KB LDS/block; waves split
// 4x1 over A-rows (wave = 32 rows x 64 cols/step, af[2][4] = 32 VGPR,
// ~110 VGPR peak under the 128 cap of __launch_bounds__(256,4));
// grid 64x16 = 1024 blocks -> 4 blocks/CU, 4 waves/SIMD from DIFFERENT
// blocks at independent phases -> one block's barrier drain is hidden by
// the other three's MFMA (the m97/m114 mechanism).
#define N_ROWS 8192
#define DIM    128
#define TILE   128
#define STEPC  64    // B-rows (output cols) staged per step
#define STEPS  8     // steps per block: 512 cols
#define EXPTEN 22026.465794806718f  // exp(10.0)
// Xb = normalize(f) * SCALE, SCALE^2 = 10*log2(e); then exp2(dot) = exp(10*<f,f>)
#define SCALE  3.7982826f

typedef __attribute__((ext_vector_type(8))) short short8;   // 8 bf16 = 4 VGPRs
typedef __attribute__((ext_vector_type(4))) float floatx4;  // MFMA C/D

#define EXP2F(x) __builtin_amdgcn_exp2f(x)

// async global->LDS DMA, 16B per lane; LDS dest = uniform base + lane*16
#define GLOAD_LDS(g, l)                                                        \
    __builtin_amdgcn_global_load_lds(                                          \
        (const __attribute__((address_space(1))) void*)(g),                    \
        (__attribute__((address_space(3))) void*)(l), 16, 0, 0)

// ---- Kernel 1: L2-normalize rows, scale, cast to bf16; zero pos/den ----
__global__ void norm_kernel(const float* __restrict__ F, __hip_bfloat16* __restrict__ Xb,
                            float* __restrict__ pos, float* __restrict__ den) {
    int lane = threadIdx.x & 63;
    int wave = threadIdx.x >> 6;
    int row  = blockIdx.x * 4 + wave;           // 2048 blocks x 4 waves = 8192 rows
    const float2 v = *(const float2*)(F + (size_t)row * DIM + lane * 2);
    float ss = v.x * v.x + v.y * v.y;
    #pragma unroll
    for (int m = 1; m < 64; m <<= 1) ss += __shfl_xor(ss, m);
    float inv = rsqrtf(ss) * SCALE;
    __hip_bfloat162 o;
    o.x = __float2bfloat16(v.x * inv);
    o.y = __float2bfloat16(v.y * inv);
    *((__hip_bfloat162*)(Xb + (size_t)row * DIM) + lane) = o;
    if (lane == 0) { pos[row] = 0.f; den[row] = 0.f; }
}

// ---- Kernel 2: fused gram + exp + row sums; small-step dbuf LDS pipeline ----
// Block (rb, cg): A rows [rb*128,+128) x cols [cg*512,+512) in 8 steps of 64.
// Wave w owns A rows [rb*128 + w*32, +32); per step: 2x4 MFMA 16x16x32 via
// af[2][4] x bf[4]. LDS chunk j holds global chunk (j&15)^(r&15) of row
// j>>4 (XOR swizzle folded into the global source; ds_read_b128 conflict-free).
// Step cols = exactly one E-block, so the pos step is cg*8+t == rb*2+(w>>1).
__global__ __launch_bounds__(256, 4) void gram_kernel(
        const __hip_bfloat16* __restrict__ Xb,
        float* __restrict__ pos, float* __restrict__ den) {
    __shared__ __hip_bfloat16 Bs[2][STEPC * DIM];   // 2 x 16 KB
    const int tid  = threadIdx.x;
    const int rb   = blockIdx.x;      // 0..63
    const int cg   = blockIdx.y;      // 0..15
    const int lane = tid & 63;
    const int wave = tid >> 6;        // 0..3
    const int quad = lane >> 4;       // 0..3
    const int l15  = lane & 15;       // 0..15

    // Stage step t into Bs[buf]: 1024 16B-chunks, 4 issues/thread, swizzled src.
    auto stage = [&](int t, int buf) {
        #pragma unroll
        for (int i = 0; i < 4; ++i) {
            int chunk = (i * 4 + wave) * 64 + lane;   // 0..1023
            int r  = chunk >> 4;                      // 0..63
            int cs = (chunk & 15) ^ (r & 15);
            const __hip_bfloat16* gp =
                Xb + ((size_t)(cg * (STEPC * STEPS) + t * STEPC + r)) * DIM + cs * 8;
            char* lp = (char*)&Bs[buf][0] + (i * 4 + wave) * 1024;  // wave-uniform
            GLOAD_LDS(gp, lp);
        }
    };

    stage(0, 0);

    // A fragments: rows rb*128 + wave*32 + mi*16 + l15, elems ko*32 + quad*8.
    short8 af[2][4];
    {
        const __hip_bfloat16* Ab =
            Xb + ((size_t)(rb * TILE + wave * 32 + l15)) * DIM + quad * 8;
        #pragma unroll
        for (int mi = 0; mi < 2; ++mi)
            #pragma unroll
            for (int ko = 0; ko < 4; ++ko)
                af[mi][ko] = *(const short8*)(Ab + mi * 16 * DIM + ko * 32);
    }

    float dp[2][4], pp[2][4];
    #pragma unroll
    for (int a = 0; a < 2; ++a)
        #pragma unroll
        for (int b = 0; b < 4; ++b) { dp[a][b] = 0.f; pp[a][b] = 0.f; }

    auto compute = [&](int t, int buf) {
        const bool pos_step = (cg * 8 + t) == (rb * 2 + (wave >> 1));
        const char* Bb = (const char*)&Bs[buf][0];
        #pragma unroll
        for (int ni = 0; ni < 4; ++ni) {
            short8 bf[4];
            #pragma unroll
            for (int ko = 0; ko < 4; ++ko) {
                int r  = ni * 16 + l15;               // 0..63
                int ch = (ko * 4 + quad) ^ l15;       // undo staging swizzle
                bf[ko] = *(const short8*)(Bb + r * 256 + ch * 16);
            }
            floatx4 acc[2];
            acc[0] = (floatx4)0.0f; acc[1] = (floatx4)0.0f;
            #pragma unroll
            for (int ko = 0; ko < 4; ++ko)
                #pragma unroll
                for (int mi = 0; mi < 2; ++mi)
                    acc[mi] = __builtin_amdgcn_mfma_f32_16x16x32_bf16(
                        af[mi][ko], bf[ko], acc[mi], 0, 0, 0);
            #pragma unroll
            for (int mi = 0; mi < 2; ++mi)
                #pragma unroll
                for (int rg = 0; rg < 4; ++rg) {
                    float ex = EXP2F(acc[mi][rg]);
                    // diagonal: replace bf16-noisy exp(10*||x||^2) with exact exp(10)
                    if (pos_step && ni == ((wave & 1) * 2 + mi) && l15 == quad * 4 + rg)
                        ex = EXPTEN;
                    dp[mi][rg] += ex;
                    if (pos_step) pp[mi][rg] += ex;
                }
        }
    };

    __syncthreads();                       // drains stage(0) + A loads
    #pragma unroll 1
    for (int t = 0; t < STEPS - 1; ++t) {
        stage(t + 1, (t + 1) & 1);         // async, drains at loop-end barrier
        compute(t, t & 1);                 // MFMA covers the staging latency
        __syncthreads();
    }
    compute(STEPS - 1, (STEPS - 1) & 1);

    // den: reduce across the 16 lanes of each quad group, one atomic per row.
    #pragma unroll
    for (int mi = 0; mi < 2; ++mi)
        #pragma unroll
        for (int rg = 0; rg < 4; ++rg) {
            float d = dp[mi][rg];
            #pragma unroll
            for (int m = 1; m < 16; m <<= 1) d += __shfl_xor(d, m);
            if (l15 == 0)
                atomicAdd(&den[rb * TILE + wave * 32 + mi * 16 + quad * 4 + rg], d);
        }
    if (cg == (rb >> 2)) {                 // this block's col range holds the positives
        #pragma unroll
        for (int mi = 0; mi < 2; ++mi)
            #pragma unroll
            for (int rg = 0; rg < 4; ++rg) {
                float p = pp[mi][rg];
                #pragma unroll
                for (int m = 1; m < 16; m <<= 1) p += __shfl_xor(p, m);
                if (l15 == 0)
                    atomicAdd(&pos[rb * TILE + wave * 32 + mi * 16 + quad * 4 + rg], p);
            }
    }
}

// ---- Kernel 3: loss = mean(log(den/pos)) ----
__global__ void loss_kernel(const float* __restrict__ pos, const float* __restrict__ den,
                            float* __restrict__ out) {
    __shared__ float red[4];
    float acc = 0.f;
    for (int i = threadIdx.x; i < N_ROWS / 4; i += 256) {
        float4 d = ((const float4*)den)[i];
        float4 p = ((const float4*)pos)[i];
        acc += __logf(d.x / p.x) + __logf(d.y / p.y) +
               __logf(d.z / p.z) + __logf(d.w / p.w);
    }
    #pragma unroll
    for (int m = 1; m < 64; m <<= 1) acc += __shfl_xor(acc, m);
    int lane = threadIdx.x & 63, w = threadIdx.x >> 6;
    if (lane == 0) red[w] = acc;
    __syncthreads();
    if (threadIdx.x == 0)
        out[0] = (red[0] + red[1] + red[2] + red[3]) * (1.0f / (float)N_ROWS);
}

extern "C" void kernel_launch(void* const* d_in, const int* in_sizes, int n_in,
                              void* d_out, int out_size, void* d_ws, size_t ws_size,
                              hipStream_t stream) {
    const float* feature = (const float*)d_in[0];
    // ws layout: pos[8192] f32 | den[8192] f32 | Xb[8192*128] bf16
    float* pos = (float*)d_ws;
    float* den = pos + N_ROWS;
    __hip_bfloat16* Xb = (__hip_bfloat16*)(den + N_ROWS);

    norm_kernel<<<N_ROWS / 4, 256, 0, stream>>>(feature, Xb, pos, den);
    gram_kernel<<<dim3(N_ROWS / TILE, N_ROWS / (STEPC * STEPS)), 256, 0, stream>>>(Xb, pos, den);
    loss_kernel<<<1, 256, 0, stream>>>(pos, den, (float*)d_out);
}

// Round 9
// 86.863 us; speedup vs baseline: 1.4623x; 1.4623x over previous
//
#include <hip/hip_runtime.h>
#include <hip/hip_bf16.h>

// feature [B=128, E=64, D=128] fp32 -> N = 8192 rows of dim 128.
// loss = mean_r( log(den_r) - log(pos_r) ),
//   den_r = sum_c exp(10*<f_r,f_c>), pos_r = sum over c in r's 64-row block.
//
// v9: v1's tile/swizzle/epilogue (the only structure that ever hit ~30us)
// + the T3/T4 counted-vmcnt schedule (m218: counted-vs-drain0 = +38..73%).
// Each 128-col tile is split into two 64-row half-tiles staged into a 4-slot
// LDS ring (4 x 16 KB). Prefetch depth 3: per half h we do
//   s_barrier; stage(h+3); s_waitcnt vmcnt(12); s_barrier; compute(h)
// using RAW s_barrier (no implicit vmcnt(0) drain, unlike __syncthreads).
// 12 loads (3 halves) are ALWAYS in flight; a half's loads land ~2000 cyc
// before its compute -> zero exposed staging latency by construction.
// Waves 2x2 over each half (64 rows x 32 cols): 32 MFMA + 32 exp2 per half.
// T5 setprio around the MFMA cluster (phase role-split now exists).
#define N_ROWS 8192
#define DIM    128
#define TILE   128
#define NHALF  16    // half-tiles per block (8 col-tiles x 2)
#define EXPTEN 22026.465794806718f  // exp(10.0)
// Xb = normalize(f) * SCALE, SCALE^2 = 10*log2(e); then exp2(dot) = exp(10*<f,f>)
#define SCALE  3.7982826f

typedef __attribute__((ext_vector_type(8))) short short8;   // 8 bf16 = 4 VGPRs
typedef __attribute__((ext_vector_type(4))) float floatx4;  // MFMA C/D

#define EXP2F(x) __builtin_amdgcn_exp2f(x)
#define BAR()    __builtin_amdgcn_s_barrier()
#define VMCNT(n) asm volatile("s_waitcnt vmcnt(" #n ")" ::: "memory")

// async global->LDS DMA, 16B per lane; LDS dest = uniform base + lane*16
#define GLOAD_LDS(g, l)                                                        \
    __builtin_amdgcn_global_load_lds(                                          \
        (const __attribute__((address_space(1))) void*)(g),                    \
        (__attribute__((address_space(3))) void*)(l), 16, 0, 0)

// ---- Kernel 1: L2-normalize rows, scale, cast to bf16; zero pos/den ----
__global__ void norm_kernel(const float* __restrict__ F, __hip_bfloat16* __restrict__ Xb,
                            float* __restrict__ pos, float* __restrict__ den) {
    int lane = threadIdx.x & 63;
    int wave = threadIdx.x >> 6;
    int row  = blockIdx.x * 4 + wave;           // 2048 blocks x 4 waves = 8192 rows
    const float2 v = *(const float2*)(F + (size_t)row * DIM + lane * 2);
    float ss = v.x * v.x + v.y * v.y;
    #pragma unroll
    for (int m = 1; m < 64; m <<= 1) ss += __shfl_xor(ss, m);
    float inv = rsqrtf(ss) * SCALE;
    __hip_bfloat162 o;
    o.x = __float2bfloat16(v.x * inv);
    o.y = __float2bfloat16(v.y * inv);
    *((__hip_bfloat162*)(Xb + (size_t)row * DIM) + lane) = o;
    if (lane == 0) { pos[row] = 0.f; den[row] = 0.f; }
}

// ---- Kernel 2: fused gram + exp + row sums; counted-vmcnt ring pipeline ----
// Block (rb, cg): A rows [rb*128,+128) x cols [cg*1024,+1024) = 16 half-tiles
// of 64 cols. LDS ring slot h&3 holds half h. XOR swizzle (chunk ^ row&15)
// folded into the GLOBAL source address so ds_read_b128 is conflict-free
// despite global_load_lds's forced-linear LDS dest (both-sides rule, m231).
__global__ __launch_bounds__(256, 2) void gram_kernel(
        const __hip_bfloat16* __restrict__ Xb,
        float* __restrict__ pos, float* __restrict__ den) {
    __shared__ __hip_bfloat16 Bs[4][64 * DIM];   // 4 ring slots x 16 KB
    const int tid  = threadIdx.x;
    const int rb   = blockIdx.x;      // 0..63
    const int cg   = blockIdx.y;      // 0..7
    const int lane = tid & 63;
    const int wave = tid >> 6;        // 0..3
    const int wm   = wave >> 1, wn = wave & 1;
    const int quad = lane >> 4;       // 0..3
    const int l15  = lane & 15;       // 0..15

    // Stage half h (64 B-rows = cols cg*1024 + h*64 ..+64) into slot h&3.
    // 1024 16B-chunks, 4 issues/thread; wave-uniform LDS base + lane*16.
    auto stage = [&](int h) {
        char* slot = (char*)&Bs[h & 3][0];
        const int colbase = cg * (NHALF * 64) + h * 64;
        #pragma unroll
        for (int i = 0; i < 4; ++i) {
            int chunk = (i * 4 + wave) * 64 + lane;   // 0..1023
            int r  = chunk >> 4;                      // 0..63
            int cs = (chunk & 15) ^ (r & 15);
            const __hip_bfloat16* gp = Xb + ((size_t)(colbase + r)) * DIM + cs * 8;
            GLOAD_LDS(gp, slot + (i * 4 + wave) * 1024);
        }
    };

    // A fragments FIRST (oldest in vmcnt queue -> drained by first VMCNT(12)).
    short8 af[4][4];
    {
        const __hip_bfloat16* Ab =
            Xb + ((size_t)(rb * TILE + wm * 64 + l15)) * DIM + quad * 8;
        #pragma unroll
        for (int mi = 0; mi < 4; ++mi)
            #pragma unroll
            for (int ko = 0; ko < 4; ++ko)
                af[mi][ko] = *(const short8*)(Ab + mi * 16 * DIM + ko * 32);
    }
    stage(0); stage(1); stage(2);          // prefetch depth 3

    float dp[4][4];   // row-sum accumulators
    #pragma unroll
    for (int a = 0; a < 4; ++a)
        #pragma unroll
        for (int b = 0; b < 4; ++b) dp[a][b] = 0.f;

    // Compute half h: wave tile 64 rows (wm) x 32 cols (wn*32, ni 0..1).
    auto compute = [&](int h) {
        const char* Bb = (const char*)&Bs[h & 3][0];
        // pos cols for this wave's rows = cols [(2rb+wm)*64,+64) = half (rb*2+wm)
        const bool pos_half = (cg * NHALF + h) == (rb * 2 + wm);

        short8 bf[2][4];
        #pragma unroll
        for (int ni = 0; ni < 2; ++ni)
            #pragma unroll
            for (int ko = 0; ko < 4; ++ko) {
                int r  = wn * 32 + ni * 16 + l15;     // 0..63 within half
                int ch = (ko * 4 + quad) ^ l15;       // undo staging swizzle
                bf[ni][ko] = *(const short8*)(Bb + r * 256 + ch * 16);
            }

        floatx4 acc[4][2];
        #pragma unroll
        for (int mi = 0; mi < 4; ++mi)
            #pragma unroll
            for (int ni = 0; ni < 2; ++ni) acc[mi][ni] = (floatx4)0.0f;

        __builtin_amdgcn_s_setprio(1);
        #pragma unroll
        for (int ko = 0; ko < 4; ++ko)
            #pragma unroll
            for (int mi = 0; mi < 4; ++mi)
                #pragma unroll
                for (int ni = 0; ni < 2; ++ni)
                    acc[mi][ni] = __builtin_amdgcn_mfma_f32_16x16x32_bf16(
                        af[mi][ko], bf[ni][ko], acc[mi][ni], 0, 0, 0);
        __builtin_amdgcn_s_setprio(0);

        if (!pos_half) {
            #pragma unroll
            for (int mi = 0; mi < 4; ++mi)
                #pragma unroll
                for (int ni = 0; ni < 2; ++ni)
                    #pragma unroll
                    for (int rg = 0; rg < 4; ++rg)
                        dp[mi][rg] += EXP2F(acc[mi][ni][rg]);
        } else {
            float padd[4][4];
            #pragma unroll
            for (int mi = 0; mi < 4; ++mi)
                #pragma unroll
                for (int rg = 0; rg < 4; ++rg) padd[mi][rg] = 0.f;
            #pragma unroll
            for (int mi = 0; mi < 4; ++mi)
                #pragma unroll
                for (int ni = 0; ni < 2; ++ni)
                    #pragma unroll
                    for (int rg = 0; rg < 4; ++rg) {
                        float ex = EXP2F(acc[mi][ni][rg]);
                        // diagonal: replace bf16-noisy exp(10*||x||^2) with exp(10)
                        if (mi == wn * 2 + ni && l15 == quad * 4 + rg)
                            ex = EXPTEN;
                        dp[mi][rg]   += ex;
                        padd[mi][rg] += ex;
                    }
            #pragma unroll
            for (int mi = 0; mi < 4; ++mi)
                #pragma unroll
                for (int rg = 0; rg < 4; ++rg) {
                    float p = padd[mi][rg];
                    #pragma unroll
                    for (int m = 1; m < 16; m <<= 1) p += __shfl_xor(p, m);
                    if (l15 == 0)
                        atomicAdd(&pos[rb * TILE + wm * 64 + mi * 16 + quad * 4 + rg], p);
                }
        }
    };

    // Main loop: 12 loads ALWAYS in flight, never vmcnt(0) until the tail.
    #pragma unroll 1
    for (int h = 0; h < NHALF - 3; ++h) {
        BAR();                 // all waves done compute(h-1): slot (h+3)&3 free
        stage(h + 3);
        VMCNT(12);             // half h landed (h+1,h+2,h+3 = 12 still in flight)
        BAR();                 // ALL waves' half-h loads landed
        compute(h);
    }
    VMCNT(8);  BAR(); compute(NHALF - 3);
    VMCNT(4);  BAR(); compute(NHALF - 2);
    VMCNT(0);  BAR(); compute(NHALF - 1);

    // den: reduce across the 16 lanes of each quad group, one atomic per row.
    #pragma unroll
    for (int mi = 0; mi < 4; ++mi)
        #pragma unroll
        for (int rg = 0; rg < 4; ++rg) {
            float d = dp[mi][rg];
            #pragma unroll
            for (int m = 1; m < 16; m <<= 1) d += __shfl_xor(d, m);
            if (l15 == 0)
                atomicAdd(&den[rb * TILE + wm * 64 + mi * 16 + quad * 4 + rg], d);
        }
}

// ---- Kernel 3: loss = mean(log(den/pos)) ----
__global__ void loss_kernel(const float* __restrict__ pos, const float* __restrict__ den,
                            float* __restrict__ out) {
    __shared__ float red[4];
    float acc = 0.f;
    for (int i = threadIdx.x; i < N_ROWS / 4; i += 256) {
        float4 d = ((const float4*)den)[i];
        float4 p = ((const float4*)pos)[i];
        acc += __logf(d.x / p.x) + __logf(d.y / p.y) +
               __logf(d.z / p.z) + __logf(d.w / p.w);
    }
    #pragma unroll
    for (int m = 1; m < 64; m <<= 1) acc += __shfl_xor(acc, m);
    int lane = threadIdx.x & 63, w = threadIdx.x >> 6;
    if (lane == 0) red[w] = acc;
    __syncthreads();
    if (threadIdx.x == 0)
        out[0] = (red[0] + red[1] + red[2] + red[3]) * (1.0f / (float)N_ROWS);
}

extern "C" void kernel_launch(void* const* d_in, const int* in_sizes, int n_in,
                              void* d_out, int out_size, void* d_ws, size_t ws_size,
                              hipStream_t stream) {
    const float* feature = (const float*)d_in[0];
    // ws layout: pos[8192] f32 | den[8192] f32 | Xb[8192*128] bf16
    float* pos = (float*)d_ws;
    float* den = pos + N_ROWS;
    __hip_bfloat16* Xb = (__hip_bfloat16*)(den + N_ROWS);

    norm_kernel<<<N_ROWS / 4, 256, 0, stream>>>(feature, Xb, pos, den);
    gram_kernel<<<dim3(64, 8), 256, 0, stream>>>(Xb, pos, den);
    loss_kernel<<<1, 256, 0, stream>>>(pos, den, (float*)d_out);
}